// Round 1
// baseline (342.805 us; speedup 1.0000x reference)
//
#include <hip/hip_runtime.h>
#include <math.h>

#define R_ 4
#define B_ 16
#define HQ_ 32
#define HKV_ 2
#define G_ 16
#define D_ 128
#define S_ 32
#define L_ 2048
#define P_ 32768
#define C_ 8      // chunks per (r,b,hkv) row
#define NSPL_ 4   // splits per chunk
#define TS_ 64    // max rows per split tile (per <= 64)
#define NEGINF (-INFINITY)

// ws layout (floats):
//   lse_split [R][B][HKV][S][G]          = 65536
//   chunk_m   [R][B][HKV][C][G]          = 16384
//   chunk_acc [R][B][HKV][C][G][D]       = 2097152
#define WS_LSE   0
#define WS_CM    65536
#define WS_CACC  (65536 + 16384)

__global__ __launch_bounds__(256) void fd_stage1(
    const float* __restrict__ q, const float* __restrict__ kc,
    const float* __restrict__ vc, const int* __restrict__ bt,
    const int* __restrict__ lens,
    float* __restrict__ lse_split, float* __restrict__ chunk_m,
    float* __restrict__ chunk_acc)
{
  const int t   = threadIdx.x;
  const int blk = blockIdx.x;
  const int c   = blk & 7;
  const int hkv = (blk >> 3) & 1;
  const int b   = (blk >> 4) & 15;
  const int r   = blk >> 8;

  const int len = lens[r*B_ + b];
  const int per = (len + S_ - 1) >> 5;   // ceil(len/32), 2..64

  __shared__ float q_s[G_][D_+4];
  __shared__ float k_s[TS_][D_+4];
  __shared__ float p_s[G_][TS_];
  __shared__ float alpha_s[G_];
  __shared__ int   page_s[TS_];

  // stage q tile for this (b, hkv): 16 heads x 128, fully coalesced
  {
    const float* qb = q + (b*HQ_ + hkv*G_)*D_;
    int f4 = t;
    #pragma unroll
    for (int i = 0; i < 2; ++i, f4 += 256) {
      int g = f4 >> 5, dd = (f4 & 31) * 4;
      *(float4*)&q_s[g][dd] = *(const float4*)&qb[g*D_ + dd];
    }
  }

  // score-phase mapping: thread owns (g = sg, n in {nl, nl+16, nl+32, nl+48})
  const int sg = t >> 4;
  const int nl = t & 15;
  // PV mapping: thread owns (d4..d4+3) x heads {gp, gp+8}
  const int d4 = (t & 31) * 4;
  const int gp = t >> 5;

  float  m_run = NEGINF;                    // per sg (redundant across its 16 lanes)
  float4 acc0 = make_float4(0.f,0.f,0.f,0.f);
  float4 acc1 = make_float4(0.f,0.f,0.f,0.f);

  const int* btb   = bt + (r*B_ + b)*L_;
  const int kvbase = r*(P_*HKV_*D_) + hkv*D_;   // element offset; < 2^31/4 ok
  float* lse_out = lse_split + ((r*B_ + b)*HKV_ + hkv)*(S_*G_);

  for (int j = 0; j < NSPL_; ++j) {
    const int s  = c*NSPL_ + j;
    const int n0 = s*per;
    const int tn = min(per, len - n0);      // block-uniform
    if (tn <= 0) {
      if (t < G_) lse_out[s*G_ + t] = NEGINF;  // empty split -> -inf
      continue;
    }
    __syncthreads();                         // protect page_s/p_s from prior tile PV
    if (t < tn) page_s[t] = btb[n0 + t];
    __syncthreads();
    // stage K rows [0, tn): 8 rows in parallel, 32 lanes x float4 per row
    for (int row = t >> 5; row < tn; row += 8) {
      const float4 kx = *(const float4*)&kc[kvbase + page_s[row]*(HKV_*D_) + ((t & 31)*4)];
      *(float4*)&k_s[row][(t & 31)*4] = kx;
    }
    __syncthreads();

    // scores: 4 dots of 128 per thread (rows >= tn read stale LDS, masked below)
    float s0 = 0.f, s1 = 0.f, s2 = 0.f, s3 = 0.f;
    #pragma unroll 8
    for (int d = 0; d < D_; d += 4) {
      const float4 q4 = *(const float4*)&q_s[sg][d];
      const float4 k0 = *(const float4*)&k_s[nl     ][d];
      const float4 k1 = *(const float4*)&k_s[nl + 16][d];
      const float4 k2 = *(const float4*)&k_s[nl + 32][d];
      const float4 k3 = *(const float4*)&k_s[nl + 48][d];
      s0 += q4.x*k0.x + q4.y*k0.y + q4.z*k0.z + q4.w*k0.w;
      s1 += q4.x*k1.x + q4.y*k1.y + q4.z*k1.z + q4.w*k1.w;
      s2 += q4.x*k2.x + q4.y*k2.y + q4.z*k2.z + q4.w*k2.w;
      s3 += q4.x*k3.x + q4.y*k3.y + q4.z*k3.z + q4.w*k3.w;
    }
    const float sc = 0.08838834764831845f;   // 128^-0.5
    float sv0 = (nl      < tn) ? s0*sc : NEGINF;
    float sv1 = (nl + 16 < tn) ? s1*sc : NEGINF;
    float sv2 = (nl + 32 < tn) ? s2*sc : NEGINF;
    float sv3 = (nl + 48 < tn) ? s3*sc : NEGINF;

    // per-(g) tile max + sumexp across the 16 lanes of this g
    float pm = fmaxf(fmaxf(sv0, sv1), fmaxf(sv2, sv3));
    #pragma unroll
    for (int off = 1; off < 16; off <<= 1)
      pm = fmaxf(pm, __shfl_xor(pm, off));
    float ps = __expf(sv0 - pm) + __expf(sv1 - pm) + __expf(sv2 - pm) + __expf(sv3 - pm);
    #pragma unroll
    for (int off = 1; off < 16; off <<= 1)
      ps += __shfl_xor(ps, off);
    const float lse  = pm + __logf(ps);      // exact per-split lse (tn>=1 -> finite)
    const float newm = fmaxf(m_run, pm);
    if (nl == 0) {
      lse_out[s*G_ + sg] = lse;
      alpha_s[sg] = __expf(m_run - newm);    // first tile: exp(-inf - finite) = 0, acc is 0 anyway
    }
    m_run = newm;
    p_s[sg][nl]      = __expf(sv0 - newm);   // invalid n -> exp(-inf) = 0
    p_s[sg][nl + 16] = __expf(sv1 - newm);
    p_s[sg][nl + 32] = __expf(sv2 - newm);
    p_s[sg][nl + 48] = __expf(sv3 - newm);
    __syncthreads();                          // p_s, alpha_s ready

    // PV: V read straight from global (same 512B row across gp groups -> L1 hits)
    const float a0 = alpha_s[gp], a1 = alpha_s[gp + 8];
    acc0.x *= a0; acc0.y *= a0; acc0.z *= a0; acc0.w *= a0;
    acc1.x *= a1; acc1.y *= a1; acc1.z *= a1; acc1.w *= a1;
    #pragma unroll 4
    for (int n = 0; n < tn; ++n) {
      const float4 v4 = *(const float4*)&vc[kvbase + page_s[n]*(HKV_*D_) + d4];
      const float p0 = p_s[gp][n], p1 = p_s[gp + 8][n];
      acc0.x += p0*v4.x; acc0.y += p0*v4.y; acc0.z += p0*v4.z; acc0.w += p0*v4.w;
      acc1.x += p1*v4.x; acc1.y += p1*v4.y; acc1.z += p1*v4.z; acc1.w += p1*v4.w;
    }
  }

  // chunk outputs (written unconditionally; empty chunk -> m=-inf, acc=0)
  if (nl == 0)
    chunk_m[(((r*B_ + b)*HKV_ + hkv)*C_ + c)*G_ + sg] = m_run;
  float* ca = chunk_acc + (size_t)((((r*B_ + b)*HKV_ + hkv)*C_ + c)*G_) * D_;
  *(float4*)&ca[gp*D_ + d4]       = acc0;
  *(float4*)&ca[(gp + 8)*D_ + d4] = acc1;
}

__global__ __launch_bounds__(128) void fd_stage2(
    const float* __restrict__ lse_split, const float* __restrict__ chunk_m,
    const float* __restrict__ chunk_acc, float* __restrict__ out)
{
  const int bh  = blockIdx.x;          // b*32 + h
  const int b   = bh >> 5, h = bh & 31;
  const int hkv = h >> 4, g = h & 15;
  const int d   = threadIdx.x;

  float m_r[R_], lse_r[R_];
  #pragma unroll
  for (int r = 0; r < R_; ++r) {
    const float* ls = lse_split + ((r*B_ + b)*HKV_ + hkv)*(S_*G_) + g;
    float m = NEGINF;
    #pragma unroll
    for (int s2 = 0; s2 < S_; ++s2) m = fmaxf(m, ls[s2*G_]);
    float sum = 0.f;
    #pragma unroll
    for (int s2 = 0; s2 < S_; ++s2) sum += __expf(ls[s2*G_] - m);  // -inf entries -> 0
    m_r[r]   = m;                       // len>=64 -> split 0 nonempty -> finite
    lse_r[r] = m + __logf(sum);
  }
  const float M = fmaxf(fmaxf(lse_r[0], lse_r[1]), fmaxf(lse_r[2], lse_r[3]));
  float denom = 0.f, o = 0.f;
  #pragma unroll
  for (int r = 0; r < R_; ++r) {
    const float w = __expf(lse_r[r] - M);
    denom += w;
    const float* cm = chunk_m  + ((r*B_ + b)*HKV_ + hkv)*(C_*G_) + g;
    const float* ca = chunk_acc + (size_t)(((r*B_ + b)*HKV_ + hkv)*(C_*G_) + g) * D_ + d;
    float a = 0.f;
    #pragma unroll
    for (int cc2 = 0; cc2 < C_; ++cc2)
      a += __expf(cm[cc2*G_] - m_r[r]) * ca[(size_t)cc2 * (G_*D_)];  // empty chunk: 0 * 0
    o += w * a;   // faithful: acc_r is UNNORMALIZED, weighted by exp(lse_r - M)
  }
  out[(size_t)bh*D_ + d] = o / denom;
}

extern "C" void kernel_launch(void* const* d_in, const int* in_sizes, int n_in,
                              void* d_out, int out_size, void* d_ws, size_t ws_size,
                              hipStream_t stream) {
  const float* q   = (const float*)d_in[0];
  const float* kc  = (const float*)d_in[1];
  const float* vc  = (const float*)d_in[2];
  const int*   bt  = (const int*)d_in[3];
  const int*   len = (const int*)d_in[4];
  float* out = (float*)d_out;
  float* ws  = (float*)d_ws;

  float* lse_split = ws + WS_LSE;
  float* chunk_m   = ws + WS_CM;
  float* chunk_acc = ws + WS_CACC;

  fd_stage1<<<dim3(R_*B_*HKV_*C_), dim3(256), 0, stream>>>(
      q, kc, vc, bt, len, lse_split, chunk_m, chunk_acc);
  fd_stage2<<<dim3(B_*HQ_), dim3(128), 0, stream>>>(
      lse_split, chunk_m, chunk_acc, out);
}